// Round 13
// baseline (125.338 us; speedup 1.0000x reference)
//
#include <hip/hip_runtime.h>

#define E 1024
#define HH 64
#define BB 4
#define SS 2048
#define BS (BB*SS)   // 8192 rows
#define NSLOT 144    // per-batch split-K slots: sum_{qt=0}^{31} (qt/4 + 1)

typedef unsigned short u16;
typedef short bf16x8 __attribute__((ext_vector_type(8)));
typedef float f32x4 __attribute__((ext_vector_type(4)));

#define LOG2E_O8 0.18033688011112042f   // log2(e)/8 : folds 1/sqrt(64) + exp2 domain

__device__ inline u16 f2bf(float f) {
    unsigned int u = __float_as_uint(f);
    unsigned int r = (u + 0x7FFFu + ((u >> 16) & 1u)) >> 16;   // RNE
    return (u16)r;
}
__device__ inline float bf2f(u16 h) {
    return __uint_as_float(((unsigned int)h) << 16);
}

// ---------- Kernel 1: LN stats (blocks 0..2047) + W'·gamma cast & beta-bias (2048..2239) ----------
// Stats: wave-per-row -> (mu, rstd) only (64 KB, not a 16.8 MB xn).
// W fold (exact, R4-verified): y_h = sum_e ((x-mu)*rstd)_e * (W*gamma*sc)[h][e] + sum_e (beta*W*sc)[h][e]
__global__ __launch_bounds__(256) void stats_wcast(const float* __restrict__ x,
        const float* __restrict__ gamma, const float* __restrict__ beta,
        const float* __restrict__ Wq, const float* __restrict__ Wk,
        const float* __restrict__ Wv,
        float* __restrict__ smu, float* __restrict__ srs,
        u16* __restrict__ wc, float* __restrict__ bias) {
    __shared__ float red[4];
    const int t = threadIdx.x;
    if (blockIdx.x < 2048) {
        // ---- LN stats: wave-per-row ----
        const int w = t >> 6, lane = t & 63;
        const size_t row = (size_t)blockIdx.x * 4 + w;
        const float4* xr = (const float4*)(x + row * E);
        float s = 0.f, sq = 0.f;
        #pragma unroll
        for (int i = 0; i < 4; ++i) {
            const float4 v = xr[lane + 64 * i];
            s  += v.x + v.y + v.z + v.w;
            sq += v.x*v.x + v.y*v.y + v.z*v.z + v.w*v.w;
        }
        #pragma unroll
        for (int off = 32; off > 0; off >>= 1) {
            s  += __shfl_xor(s,  off);
            sq += __shfl_xor(sq, off);
        }
        if (lane == 0) {
            const float mean = s * (1.0f / E);
            const float var  = sq * (1.0f / E) - mean * mean;
            smu[row] = mean;
            srs[row] = rsqrtf(var + 1e-5f);
        }
    } else {
        // ---- W cast -> bf16 (gamma folded; Wq rows pre-scaled by log2(e)/8) + bias ----
        const int row = blockIdx.x - 2048;   // 0..191
        const float* src = (row < 64)  ? (Wq + (size_t)row * E)
                         : (row < 128) ? (Wk + (size_t)(row - 64) * E)
                                       : (Wv + (size_t)(row - 128) * E);
        const float sc = (row < 64) ? LOG2E_O8 : 1.0f;
        const float4 v = *(const float4*)(src + t * 4);
        const float4 g = *(const float4*)(gamma + t * 4);
        const float4 b = *(const float4*)(beta  + t * 4);
        ushort4 o;
        o.x = f2bf(v.x * g.x * sc); o.y = f2bf(v.y * g.y * sc);
        o.z = f2bf(v.z * g.z * sc); o.w = f2bf(v.w * g.w * sc);
        *(ushort4*)(wc + (size_t)row * E + t * 4) = o;

        float s = (v.x * b.x + v.y * b.y + v.z * b.z + v.w * b.w) * sc;
        #pragma unroll
        for (int off = 32; off > 0; off >>= 1) s += __shfl_xor(s, off);
        if ((t & 63) == 0) red[t >> 6] = s;
        __syncthreads();
        if (t == 0) bias[row] = red[0] + red[1] + red[2] + red[3];
    }
}

// ---------- Kernel 2: fused LN-normalize + QKV projection (MFMA bf16) ----------
// R12 structure (32x96 blocks, 128-k chunks, 16 pipelined rounds). Staging source is
// raw fp32 x, normalized in-register ((x-mu)*rstd -> bf16) during the existing staging
// step; each staging thread owns one fixed row so mu/rs live in 2 VGPRs (loaded once).
// Epilogue adds beta-bias. V written pre-transposed vt[b][h][key].
__global__ __launch_bounds__(256) void qkv_mfma(const float* __restrict__ x,
        const float* __restrict__ smu, const float* __restrict__ srs,
        const u16* __restrict__ wc, const float* __restrict__ bias,
        u16* __restrict__ qb, u16* __restrict__ kb, u16* __restrict__ vt) {
    const int mb   = blockIdx.x >> 1;
    const int half = blockIdx.x & 1;
    const int row0 = mb * 32;
    const int t = threadIdx.x;
    const int w = t >> 6, lane = t & 63;
    const int quad = lane >> 4, r15 = lane & 15;
    const int mt = w >> 1, cgrp = w & 1;
    __shared__ u16 Xs[32 * 128];   // 8 KB, per-64k-half chunk swizzle: phys = ch ^ (row&7)
    __shared__ u16 Ws[96 * 128];   // 24 KB
    f32x4 acc[3] = {};
    const int xrow = mt * 16 + r15;

    // staging thread's fixed row + its LN stats (2 VGPRs, loaded once)
    const int srow = t >> 3, sch = t & 7;
    const float mu = smu[row0 + srow];
    const float rs = srs[row0 + srow];
    const float* xsrc = x + (size_t)(row0 + srow) * E;

    // per-thread epilogue bias
    float bj[3];
    #pragma unroll
    for (int j = 0; j < 3; ++j) bj[j] = bias[half * 96 + cgrp * 48 + j * 16 + r15];

    for (int kc8 = 0; kc8 < 8; ++kc8) {
        __syncthreads();
        {   // stage X tile: 32 rows x 128 k, fp32 -> normalized bf16 in-register
            #pragma unroll
            for (int hf = 0; hf < 2; ++hf) {
                const float* sp = xsrc + kc8 * 128 + hf * 64 + sch * 8;
                const float4 f0 = *(const float4*)sp;
                const float4 f1 = *(const float4*)(sp + 4);
                u16 tmp[8];
                tmp[0] = f2bf((f0.x - mu) * rs); tmp[1] = f2bf((f0.y - mu) * rs);
                tmp[2] = f2bf((f0.z - mu) * rs); tmp[3] = f2bf((f0.w - mu) * rs);
                tmp[4] = f2bf((f1.x - mu) * rs); tmp[5] = f2bf((f1.y - mu) * rs);
                tmp[6] = f2bf((f1.z - mu) * rs); tmp[7] = f2bf((f1.w - mu) * rs);
                *(uint4*)&Xs[srow * 128 + hf * 64 + (sch ^ (srow & 7)) * 8] = *(uint4*)tmp;
            }
        }
        #pragma unroll
        for (int i = 0; i < 6; ++i) {   // stage W tile: 96 rows x 128 k
            const int idx = i * 256 + t;
            const int wl = idx >> 4, ch16 = idx & 15;
            const int hf = ch16 >> 3, ch = ch16 & 7;
            const uint4 d = *(const uint4*)(wc + (size_t)(half * 96 + wl) * E
                                            + kc8 * 128 + hf * 64 + ch * 8);
            *(uint4*)&Ws[wl * 128 + hf * 64 + (ch ^ (wl & 7)) * 8] = d;
        }
        __syncthreads();
        #pragma unroll
        for (int kk = 0; kk < 4; ++kk) {
            const int hf = kk >> 1, q4 = (kk & 1) * 4 + quad;
            const bf16x8 af = *(const bf16x8*)&Xs[xrow * 128 + hf * 64 + (q4 ^ (xrow & 7)) * 8];
            #pragma unroll
            for (int j = 0; j < 3; ++j) {
                const int wl = (cgrp * 3 + j) * 16 + r15;
                const bf16x8 bfr = *(const bf16x8*)&Ws[wl * 128 + hf * 64 + (q4 ^ (wl & 7)) * 8];
                acc[j] = __builtin_amdgcn_mfma_f32_16x16x32_bf16(af, bfr, acc[j], 0, 0, 0);
            }
        }
    }
    const int b    = row0 >> 11;
    const int key0 = row0 & 2047;
    #pragma unroll
    for (int j = 0; j < 3; ++j) {
        const int cg  = half * 96 + cgrp * 48 + j * 16 + r15;
        const int sel = cg >> 6;
        const int col = cg & 63;
        if (sel < 2) {
            u16* base = (sel == 0) ? qb : kb;
            #pragma unroll
            for (int r = 0; r < 4; ++r) {
                const size_t row = (size_t)row0 + mt * 16 + quad * 4 + r;
                base[row * HH + col] = f2bf(acc[j][r] + bj[j]);
            }
        } else {
            ushort4 pk;
            pk.x = f2bf(acc[j][0] + bj[j]); pk.y = f2bf(acc[j][1] + bj[j]);
            pk.z = f2bf(acc[j][2] + bj[j]); pk.w = f2bf(acc[j][3] + bj[j]);
            *(ushort4*)(vt + (size_t)b * HH * SS + (size_t)col * SS
                           + key0 + mt * 16 + quad * 4) = pk;
        }
    }
}

// ---------- Kernel 3: split-K causal flash attention — whole-chunk staging (R12) ----------
__global__ __launch_bounds__(256) void attn_partial(const u16* __restrict__ qb,
        const u16* __restrict__ kb, const u16* __restrict__ vt,
        u16* __restrict__ po, float* __restrict__ pl,
        float* __restrict__ out) {
    const int bid = blockIdx.x;
    const int b   = bid >> 8;
    const int rem = bid & 255;
    const int qt  = rem >> 3, c = rem & 7;
    const int a   = qt >> 2;
    if (c > a) return;                       // nc(qt) = a+1 chunks
    const int nc   = a + 1;
    const int r_   = qt & 3;
    const int slot = b * NSLOT + 2 * a * (a + 1) + r_ * (a + 1) + c;
    const int q0   = qt << 6;
    const int t = threadIdx.x;
    const int w = t >> 6, lane = t & 63;
    const int quad = lane >> 4, r15 = lane & 15;

    __shared__ u16 Ks[4 * 64 * 64];   // 32 KB: [tile][key][h], XOR-swizzled chunks
    __shared__ u16 VT[4 * 64 * 64];   // 32 KB: [tile][h][key], XOR-swizzled chunks
    __shared__ u16 Ps[64 * 64];       // 8 KB:  [qrow][key], per-wave strips

    const size_t qrow = ((size_t)b * SS + q0 + w * 16 + r15) * HH;
    const bf16x8 qf0 = *(const bf16x8*)(qb + qrow + quad * 8);
    const bf16x8 qf1 = *(const bf16x8*)(qb + qrow + 32 + quad * 8);

    const int ntiles = min(c * 4 + 4, qt + 1) - c * 4;   // 1..4

    // ---- stage ALL tiles in one burst ----
    {
        const int row = t >> 2, ch0 = (t & 3) * 2;
        for (int tl = 0; tl < ntiles; ++tl) {
            const int kt = (c * 4 + tl) << 6;
            const uint4* srcK = (const uint4*)(kb + ((size_t)b * SS + kt + row) * HH + ch0 * 8);
            const uint4 k0 = srcK[0], k1 = srcK[1];
            *(uint4*)&Ks[tl * 4096 + row * 64 + ((ch0    ) ^ (row & 7)) * 8] = k0;
            *(uint4*)&Ks[tl * 4096 + row * 64 + ((ch0 + 1) ^ (row & 7)) * 8] = k1;
            const uint4* srcV = (const uint4*)(vt + (size_t)b * HH * SS + (size_t)row * SS
                                               + kt + ch0 * 8);
            const uint4 v0 = srcV[0], v1 = srcV[1];
            *(uint4*)&VT[tl * 4096 + row * 64 + ((ch0    ) ^ (row & 7)) * 8] = v0;
            *(uint4*)&VT[tl * 4096 + row * 64 + ((ch0 + 1) ^ (row & 7)) * 8] = v1;
        }
    }
    __syncthreads();   // the ONLY block-wide barrier

    f32x4 o[4] = {};
    float l_[4] = {0.f, 0.f, 0.f, 0.f};

    for (int tl = 0; tl < ntiles; ++tl) {
        const int tile = c * 4 + tl;
        const u16* KsT = &Ks[tl * 4096];
        const u16* VTT = &VT[tl * 4096];

        f32x4 s[4] = {};
        #pragma unroll
        for (int nt = 0; nt < 4; ++nt) {
            const int krow = nt * 16 + r15;
            const bf16x8 k0 = *(const bf16x8*)&KsT[krow * 64 + ((    quad) ^ (krow & 7)) * 8];
            const bf16x8 k1 = *(const bf16x8*)&KsT[krow * 64 + ((4 + quad) ^ (krow & 7)) * 8];
            s[nt] = __builtin_amdgcn_mfma_f32_16x16x32_bf16(qf0, k0, s[nt], 0, 0, 0);
            s[nt] = __builtin_amdgcn_mfma_f32_16x16x32_bf16(qf1, k1, s[nt], 0, 0, 0);
        }
        if (tile == qt) {   // diagonal tile: mask key > query
            #pragma unroll
            for (int nt = 0; nt < 4; ++nt)
                #pragma unroll
                for (int r = 0; r < 4; ++r)
                    if (nt * 16 + r15 > w * 16 + quad * 4 + r) s[nt][r] = -INFINITY;
        }

        // un-shifted softmax: p = exp2(s) (bounded). Row sums deferred (per-lane).
        float p[4][4];
        #pragma unroll
        for (int r = 0; r < 4; ++r) {
            #pragma unroll
            for (int nt = 0; nt < 4; ++nt)
                p[nt][r] = __builtin_amdgcn_exp2f(s[nt][r]);
            l_[r] += (p[0][r] + p[1][r]) + (p[2][r] + p[3][r]);
        }

        // P strip -> LDS (C-layout write), read back as A-frags (same wave only)
        #pragma unroll
        for (int nt = 0; nt < 4; ++nt)
            #pragma unroll
            for (int r = 0; r < 4; ++r) {
                const int prow = w * 16 + quad * 4 + r;
                const int col  = nt * 16 + r15;
                Ps[prow * 64 + (((col >> 3) ^ (prow & 7)) * 8) + (col & 7)] = f2bf(p[nt][r]);
            }
        const int arow = w * 16 + r15;
        const bf16x8 pf0 = *(const bf16x8*)&Ps[arow * 64 + ((    quad) ^ (arow & 7)) * 8];
        const bf16x8 pf1 = *(const bf16x8*)&Ps[arow * 64 + ((4 + quad) ^ (arow & 7)) * 8];

        // O strip += P V
        #pragma unroll
        for (int ht = 0; ht < 4; ++ht) {
            const int vrow = ht * 16 + r15;
            const bf16x8 v0 = *(const bf16x8*)&VTT[vrow * 64 + ((    quad) ^ (vrow & 7)) * 8];
            const bf16x8 v1 = *(const bf16x8*)&VTT[vrow * 64 + ((4 + quad) ^ (vrow & 7)) * 8];
            o[ht] = __builtin_amdgcn_mfma_f32_16x16x32_bf16(pf0, v0, o[ht], 0, 0, 0);
            o[ht] = __builtin_amdgcn_mfma_f32_16x16x32_bf16(pf1, v1, o[ht], 0, 0, 0);
        }
    }

    // one row-sum reduction per block
    #pragma unroll
    for (int r = 0; r < 4; ++r) {
        l_[r] += __shfl_xor(l_[r], 1); l_[r] += __shfl_xor(l_[r], 2);
        l_[r] += __shfl_xor(l_[r], 4); l_[r] += __shfl_xor(l_[r], 8);
    }

    if (nc == 1) {   // qt<=3: this block saw all keys -> write out directly
        #pragma unroll
        for (int r = 0; r < 4; ++r) {
            const float inv = 1.0f / l_[r];
            const size_t orow = ((size_t)b * SS + q0 + w * 16 + quad * 4 + r) * HH;
            #pragma unroll
            for (int ht = 0; ht < 4; ++ht)
                out[orow + ht * 16 + r15] = o[ht][r] * inv;
        }
        return;
    }
    #pragma unroll
    for (int r = 0; r < 4; ++r) {
        const int q = w * 16 + quad * 4 + r;
        #pragma unroll
        for (int ht = 0; ht < 4; ++ht)
            po[(size_t)slot * 4096 + q * 64 + ht * 16 + r15] = f2bf(o[ht][r]);
        if (r15 == 0) pl[slot * 64 + q] = l_[r];
    }
}

// ---------- Kernel 4: split-K reduce — plain sums (po is bf16) ----------
__global__ __launch_bounds__(256) void attn_reduce(const u16* __restrict__ po,
        const float* __restrict__ pl, float* __restrict__ out) {
    const int bid = blockIdx.x;            // BB*32*4
    const int b = bid >> 7, rem = bid & 127;
    const int qt = rem >> 2, qq = rem & 3;
    if (qt < 4) return;                    // qt<=3 written directly
    const int a = qt >> 2, r_ = qt & 3;
    const int nc = a + 1;
    const int sbase = b * NSLOT + 2 * a * (a + 1) + r_ * (a + 1);
    const int t = threadIdx.x;
    const int h = t & 63, qr = t >> 6;
    #pragma unroll
    for (int i = 0; i < 4; ++i) {
        const int q = qq * 16 + qr * 4 + i;   // query within 64-tile
        float osum = 0.f, lsum = 0.f;
        for (int cidx = 0; cidx < nc; ++cidx) {
            osum += bf2f(po[(size_t)(sbase + cidx) * 4096 + q * 64 + h]);
            lsum += pl[(sbase + cidx) * 64 + q];
        }
        out[((size_t)b * SS + (qt << 6) + q) * HH + h] = osum / lsum;
    }
}

// ---------- launch ----------
extern "C" void kernel_launch(void* const* d_in, const int* in_sizes, int n_in,
                              void* d_out, int out_size, void* d_ws, size_t ws_size,
                              hipStream_t stream) {
    const float* x     = (const float*)d_in[0];
    const float* gamma = (const float*)d_in[1];
    const float* beta  = (const float*)d_in[2];
    const float* Wq    = (const float*)d_in[3];
    const float* Wk    = (const float*)d_in[4];
    const float* Wv    = (const float*)d_in[5];
    float* out = (float*)d_out;

    // ws layout: smu 32KB | srs 32KB | wc 384KB | bias 1KB | qb/kb/vt 1MB each
    //            | po 4.72MB (bf16) | pl 144KB
    char* p = (char*)d_ws;
    float* smu  = (float*)p;                       p += (size_t)BS * 4;
    float* srs  = (float*)p;                       p += (size_t)BS * 4;
    u16*   wc   = (u16*)p;                         p += 393216;
    float* bias = (float*)p;                       p += 1024;
    u16*   qb   = (u16*)p;                         p += (size_t)BS * HH * 2;
    u16*   kb   = (u16*)p;                         p += (size_t)BS * HH * 2;
    u16*   vt   = (u16*)p;                         p += (size_t)BS * HH * 2;
    u16*   po   = (u16*)p;                         p += (size_t)BB * NSLOT * 4096 * 2;
    float* pl   = (float*)p;

    stats_wcast <<<2048 + 192,  256, 0, stream>>>(x, gamma, beta, Wq, Wk, Wv,
                                                  smu, srs, wc, bias);
    qkv_mfma    <<<BS / 16,     256, 0, stream>>>(x, smu, srs, wc, bias, qb, kb, vt);
    attn_partial<<<BB * 32 * 8, 256, 0, stream>>>(qb, kb, vt, po, pl, out);
    attn_reduce <<<BB * 32 * 4, 256, 0, stream>>>(po, pl, out);
}

// Round 14
// 118.802 us; speedup vs baseline: 1.0550x; 1.0550x over previous
//
#include <hip/hip_runtime.h>

#define E 1024
#define HH 64
#define BB 4
#define SS 2048
#define BS (BB*SS)   // 8192 rows
#define NSLOT 144    // per-batch split-K slots: sum_{qt=0}^{31} (qt/4 + 1)

typedef unsigned short u16;
typedef short bf16x8 __attribute__((ext_vector_type(8)));
typedef float f32x4 __attribute__((ext_vector_type(4)));

#define LOG2E_O8 0.18033688011112042f   // log2(e)/8 : folds 1/sqrt(64) + exp2 domain

__device__ inline u16 f2bf(float f) {
    unsigned int u = __float_as_uint(f);
    unsigned int r = (u + 0x7FFFu + ((u >> 16) & 1u)) >> 16;   // RNE
    return (u16)r;
}
__device__ inline float bf2f(u16 h) {
    return __uint_as_float(((unsigned int)h) << 16);
}

// ---------- Kernel 1: fused LayerNorm (blocks 0..2047) + W cast (blocks 2048..2239) ----------
__global__ __launch_bounds__(256) void ln_wcast(const float* __restrict__ x,
        const float* __restrict__ gamma, const float* __restrict__ beta,
        const float* __restrict__ Wq, const float* __restrict__ Wk,
        const float* __restrict__ Wv,
        u16* __restrict__ xn, u16* __restrict__ wc) {
    const int t = threadIdx.x;
    if (blockIdx.x < 2048) {
        // ---- LayerNorm: wave-per-row, fp32 -> bf16 (gamma/beta applied here) ----
        const int w = t >> 6, lane = t & 63;
        const size_t row = (size_t)blockIdx.x * 4 + w;
        const float4* xr = (const float4*)(x + row * E);
        float4 v[4];
        #pragma unroll
        for (int i = 0; i < 4; ++i) v[i] = xr[lane + 64 * i];
        float s = 0.f, sq = 0.f;
        #pragma unroll
        for (int i = 0; i < 4; ++i) {
            s  += v[i].x + v[i].y + v[i].z + v[i].w;
            sq += v[i].x*v[i].x + v[i].y*v[i].y + v[i].z*v[i].z + v[i].w*v[i].w;
        }
        #pragma unroll
        for (int off = 32; off > 0; off >>= 1) {
            s  += __shfl_xor(s,  off);
            sq += __shfl_xor(sq, off);
        }
        const float mean = s * (1.0f / E);
        const float var  = sq * (1.0f / E) - mean * mean;
        const float rstd = rsqrtf(var + 1e-5f);
        const float4* gr = (const float4*)gamma;
        const float4* br = (const float4*)beta;
        #pragma unroll
        for (int i = 0; i < 4; ++i) {
            const float4 g  = gr[lane + 64 * i];
            const float4 bt = br[lane + 64 * i];
            ushort4 o;
            o.x = f2bf((v[i].x - mean) * rstd * g.x + bt.x);
            o.y = f2bf((v[i].y - mean) * rstd * g.y + bt.y);
            o.z = f2bf((v[i].z - mean) * rstd * g.z + bt.z);
            o.w = f2bf((v[i].w - mean) * rstd * g.w + bt.w);
            *(ushort4*)(xn + row * E + (lane + 64 * i) * 4) = o;
        }
    } else {
        // ---- W cast -> bf16 (Wq rows pre-scaled by log2(e)/8) ----
        const int row = blockIdx.x - 2048;   // 0..191
        const float* src = (row < 64)  ? (Wq + (size_t)row * E)
                         : (row < 128) ? (Wk + (size_t)(row - 64) * E)
                                       : (Wv + (size_t)(row - 128) * E);
        const float sc = (row < 64) ? LOG2E_O8 : 1.0f;
        const float4 v = *(const float4*)(src + t * 4);
        ushort4 o;
        o.x = f2bf(v.x * sc); o.y = f2bf(v.y * sc);
        o.z = f2bf(v.z * sc); o.w = f2bf(v.w * sc);
        *(ushort4*)(wc + (size_t)row * E + t * 4) = o;
    }
}

// ---------- Kernel 2: QKV projection, MFMA bf16, 32x96 blocks, 128-k chunks (R12) ----------
// V written pre-transposed: vt[b][h][key]
__global__ __launch_bounds__(256) void qkv_mfma(const u16* __restrict__ xn,
        const u16* __restrict__ wc,
        u16* __restrict__ qb, u16* __restrict__ kb, u16* __restrict__ vt) {
    const int mb   = blockIdx.x >> 1;
    const int half = blockIdx.x & 1;
    const int row0 = mb * 32;
    const int t = threadIdx.x;
    const int w = t >> 6, lane = t & 63;
    const int quad = lane >> 4, r15 = lane & 15;
    const int mt = w >> 1, cgrp = w & 1;
    __shared__ u16 Xs[32 * 128];   // 8 KB, per-64k-half chunk swizzle: phys = ch ^ (row&7)
    __shared__ u16 Ws[96 * 128];   // 24 KB
    f32x4 acc[3] = {};
    const int xrow = mt * 16 + r15;

    for (int kc8 = 0; kc8 < 8; ++kc8) {
        __syncthreads();
        {   // stage X tile: 32 rows x 128 k (two uint4 per thread)
            const int row = t >> 3, ch = t & 7;
            #pragma unroll
            for (int hf = 0; hf < 2; ++hf) {
                const uint4 d = *(const uint4*)(xn + (size_t)(row0 + row) * E
                                                + kc8 * 128 + hf * 64 + ch * 8);
                *(uint4*)&Xs[row * 128 + hf * 64 + (ch ^ (row & 7)) * 8] = d;
            }
        }
        #pragma unroll
        for (int i = 0; i < 6; ++i) {   // stage W tile: 96 rows x 128 k
            const int idx = i * 256 + t;
            const int wl = idx >> 4, ch16 = idx & 15;
            const int hf = ch16 >> 3, ch = ch16 & 7;
            const uint4 d = *(const uint4*)(wc + (size_t)(half * 96 + wl) * E
                                            + kc8 * 128 + hf * 64 + ch * 8);
            *(uint4*)&Ws[wl * 128 + hf * 64 + (ch ^ (wl & 7)) * 8] = d;
        }
        __syncthreads();
        #pragma unroll
        for (int kk = 0; kk < 4; ++kk) {
            const int hf = kk >> 1, q4 = (kk & 1) * 4 + quad;
            const bf16x8 af = *(const bf16x8*)&Xs[xrow * 128 + hf * 64 + (q4 ^ (xrow & 7)) * 8];
            #pragma unroll
            for (int j = 0; j < 3; ++j) {
                const int wl = (cgrp * 3 + j) * 16 + r15;
                const bf16x8 bfr = *(const bf16x8*)&Ws[wl * 128 + hf * 64 + (q4 ^ (wl & 7)) * 8];
                acc[j] = __builtin_amdgcn_mfma_f32_16x16x32_bf16(af, bfr, acc[j], 0, 0, 0);
            }
        }
    }
    const int b    = row0 >> 11;
    const int key0 = row0 & 2047;
    #pragma unroll
    for (int j = 0; j < 3; ++j) {
        const int cg  = half * 96 + cgrp * 48 + j * 16 + r15;
        const int sel = cg >> 6;
        const int col = cg & 63;
        if (sel < 2) {
            u16* base = (sel == 0) ? qb : kb;
            #pragma unroll
            for (int r = 0; r < 4; ++r) {
                const size_t row = (size_t)row0 + mt * 16 + quad * 4 + r;
                base[row * HH + col] = f2bf(acc[j][r]);
            }
        } else {
            ushort4 pk;
            pk.x = f2bf(acc[j][0]); pk.y = f2bf(acc[j][1]);
            pk.z = f2bf(acc[j][2]); pk.w = f2bf(acc[j][3]);
            *(ushort4*)(vt + (size_t)b * HH * SS + (size_t)col * SS
                           + key0 + mt * 16 + quad * 4) = pk;
        }
    }
}

// ---------- Kernel 3: split-K causal flash attention — whole-chunk staging (R12) ----------
// Grid = exactly BB*NSLOT active blocks; (a, r, c) decoded from flat slot id:
// a = floor((sqrt(2s+1)-1)/2), verified at group boundaries + fixup guards.
__global__ __launch_bounds__(256) void attn_partial(const u16* __restrict__ qb,
        const u16* __restrict__ kb, const u16* __restrict__ vt,
        u16* __restrict__ po, float* __restrict__ pl,
        float* __restrict__ out) {
    const int bid = blockIdx.x;
    const int b   = bid / NSLOT;
    const int s   = bid - b * NSLOT;            // flat slot 0..143
    int a = (int)((sqrtf(2.0f * s + 1.0f) - 1.0f) * 0.5f);
    while (2 * (a + 1) * (a + 2) <= s) ++a;     // fixup (fp edge safety)
    while (2 * a * (a + 1) > s) --a;
    const int rem = s - 2 * a * (a + 1);
    const int r_  = rem / (a + 1);
    const int c   = rem - r_ * (a + 1);
    const int qt  = 4 * a + r_;
    const int nc   = a + 1;
    const int slot = b * NSLOT + s;
    const int q0   = qt << 6;
    const int t = threadIdx.x;
    const int w = t >> 6, lane = t & 63;
    const int quad = lane >> 4, r15 = lane & 15;

    __shared__ u16 Ks[4 * 64 * 64];   // 32 KB: [tile][key][h], XOR-swizzled chunks
    __shared__ u16 VT[4 * 64 * 64];   // 32 KB: [tile][h][key], XOR-swizzled chunks
    __shared__ u16 Ps[64 * 64];       // 8 KB:  [qrow][key], per-wave strips

    const size_t qrow = ((size_t)b * SS + q0 + w * 16 + r15) * HH;
    const bf16x8 qf0 = *(const bf16x8*)(qb + qrow + quad * 8);
    const bf16x8 qf1 = *(const bf16x8*)(qb + qrow + 32 + quad * 8);

    const int ntiles = min(c * 4 + 4, qt + 1) - c * 4;   // 1..4

    // ---- stage ALL tiles in one burst ----
    {
        const int row = t >> 2, ch0 = (t & 3) * 2;
        for (int tl = 0; tl < ntiles; ++tl) {
            const int kt = (c * 4 + tl) << 6;
            const uint4* srcK = (const uint4*)(kb + ((size_t)b * SS + kt + row) * HH + ch0 * 8);
            const uint4 k0 = srcK[0], k1 = srcK[1];
            *(uint4*)&Ks[tl * 4096 + row * 64 + ((ch0    ) ^ (row & 7)) * 8] = k0;
            *(uint4*)&Ks[tl * 4096 + row * 64 + ((ch0 + 1) ^ (row & 7)) * 8] = k1;
            const uint4* srcV = (const uint4*)(vt + (size_t)b * HH * SS + (size_t)row * SS
                                               + kt + ch0 * 8);
            const uint4 v0 = srcV[0], v1 = srcV[1];
            *(uint4*)&VT[tl * 4096 + row * 64 + ((ch0    ) ^ (row & 7)) * 8] = v0;
            *(uint4*)&VT[tl * 4096 + row * 64 + ((ch0 + 1) ^ (row & 7)) * 8] = v1;
        }
    }
    __syncthreads();   // the ONLY block-wide barrier

    f32x4 o[4] = {};
    float l_[4] = {0.f, 0.f, 0.f, 0.f};

    for (int tl = 0; tl < ntiles; ++tl) {
        const int tile = c * 4 + tl;
        const u16* KsT = &Ks[tl * 4096];
        const u16* VTT = &VT[tl * 4096];

        f32x4 s4[4] = {};
        #pragma unroll
        for (int nt = 0; nt < 4; ++nt) {
            const int krow = nt * 16 + r15;
            const bf16x8 k0 = *(const bf16x8*)&KsT[krow * 64 + ((    quad) ^ (krow & 7)) * 8];
            const bf16x8 k1 = *(const bf16x8*)&KsT[krow * 64 + ((4 + quad) ^ (krow & 7)) * 8];
            s4[nt] = __builtin_amdgcn_mfma_f32_16x16x32_bf16(qf0, k0, s4[nt], 0, 0, 0);
            s4[nt] = __builtin_amdgcn_mfma_f32_16x16x32_bf16(qf1, k1, s4[nt], 0, 0, 0);
        }
        if (tile == qt) {   // diagonal tile: mask key > query
            #pragma unroll
            for (int nt = 0; nt < 4; ++nt)
                #pragma unroll
                for (int r = 0; r < 4; ++r)
                    if (nt * 16 + r15 > w * 16 + quad * 4 + r) s4[nt][r] = -INFINITY;
        }

        // un-shifted softmax: p = exp2(s) (bounded). Row sums deferred (per-lane).
        float p[4][4];
        #pragma unroll
        for (int r = 0; r < 4; ++r) {
            #pragma unroll
            for (int nt = 0; nt < 4; ++nt)
                p[nt][r] = __builtin_amdgcn_exp2f(s4[nt][r]);
            l_[r] += (p[0][r] + p[1][r]) + (p[2][r] + p[3][r]);
        }

        // P strip -> LDS (C-layout write), read back as A-frags (same wave only)
        #pragma unroll
        for (int nt = 0; nt < 4; ++nt)
            #pragma unroll
            for (int r = 0; r < 4; ++r) {
                const int prow = w * 16 + quad * 4 + r;
                const int col  = nt * 16 + r15;
                Ps[prow * 64 + (((col >> 3) ^ (prow & 7)) * 8) + (col & 7)] = f2bf(p[nt][r]);
            }
        const int arow = w * 16 + r15;
        const bf16x8 pf0 = *(const bf16x8*)&Ps[arow * 64 + ((    quad) ^ (arow & 7)) * 8];
        const bf16x8 pf1 = *(const bf16x8*)&Ps[arow * 64 + ((4 + quad) ^ (arow & 7)) * 8];

        // O strip += P V
        #pragma unroll
        for (int ht = 0; ht < 4; ++ht) {
            const int vrow = ht * 16 + r15;
            const bf16x8 v0 = *(const bf16x8*)&VTT[vrow * 64 + ((    quad) ^ (vrow & 7)) * 8];
            const bf16x8 v1 = *(const bf16x8*)&VTT[vrow * 64 + ((4 + quad) ^ (vrow & 7)) * 8];
            o[ht] = __builtin_amdgcn_mfma_f32_16x16x32_bf16(pf0, v0, o[ht], 0, 0, 0);
            o[ht] = __builtin_amdgcn_mfma_f32_16x16x32_bf16(pf1, v1, o[ht], 0, 0, 0);
        }
    }

    // one row-sum reduction per block
    #pragma unroll
    for (int r = 0; r < 4; ++r) {
        l_[r] += __shfl_xor(l_[r], 1); l_[r] += __shfl_xor(l_[r], 2);
        l_[r] += __shfl_xor(l_[r], 4); l_[r] += __shfl_xor(l_[r], 8);
    }

    if (nc == 1) {   // qt<=3: this block saw all keys -> write out directly
        #pragma unroll
        for (int r = 0; r < 4; ++r) {
            const float inv = 1.0f / l_[r];
            const size_t orow = ((size_t)b * SS + q0 + w * 16 + quad * 4 + r) * HH;
            #pragma unroll
            for (int ht = 0; ht < 4; ++ht)
                out[orow + ht * 16 + r15] = o[ht][r] * inv;
        }
        return;
    }
    #pragma unroll
    for (int r = 0; r < 4; ++r) {
        const int q = w * 16 + quad * 4 + r;
        #pragma unroll
        for (int ht = 0; ht < 4; ++ht)
            po[(size_t)slot * 4096 + q * 64 + ht * 16 + r15] = f2bf(o[ht][r]);
        if (r15 == 0) pl[slot * 64 + q] = l_[r];
    }
}

// ---------- Kernel 4: split-K reduce — plain sums (po is bf16), qt>=4 only ----------
__global__ __launch_bounds__(256) void attn_reduce(const u16* __restrict__ po,
        const float* __restrict__ pl, float* __restrict__ out) {
    const int bid = blockIdx.x;            // BB*28*4 = 448 (qt 4..31 only)
    const int b = bid / 112, rem = bid - b * 112;
    const int qt = 4 + (rem >> 2), qq = rem & 3;
    const int a = qt >> 2, r_ = qt & 3;
    const int nc = a + 1;
    const int sbase = b * NSLOT + 2 * a * (a + 1) + r_ * (a + 1);
    const int t = threadIdx.x;
    const int h = t & 63, qr = t >> 6;
    #pragma unroll
    for (int i = 0; i < 4; ++i) {
        const int q = qq * 16 + qr * 4 + i;   // query within 64-tile
        float osum = 0.f, lsum = 0.f;
        for (int cidx = 0; cidx < nc; ++cidx) {
            osum += bf2f(po[(size_t)(sbase + cidx) * 4096 + q * 64 + h]);
            lsum += pl[(sbase + cidx) * 64 + q];
        }
        out[((size_t)b * SS + (qt << 6) + q) * HH + h] = osum / lsum;
    }
}

// ---------- launch ----------
extern "C" void kernel_launch(void* const* d_in, const int* in_sizes, int n_in,
                              void* d_out, int out_size, void* d_ws, size_t ws_size,
                              hipStream_t stream) {
    const float* x     = (const float*)d_in[0];
    const float* gamma = (const float*)d_in[1];
    const float* beta  = (const float*)d_in[2];
    const float* Wq    = (const float*)d_in[3];
    const float* Wk    = (const float*)d_in[4];
    const float* Wv    = (const float*)d_in[5];
    float* out = (float*)d_out;

    // ws layout: xn 16.78MB | wc 384KB | qb/kb/vt 1MB each | po 4.72MB (bf16) | pl 144KB
    char* p = (char*)d_ws;
    u16*   xn   = (u16*)p;                         p += (size_t)BS * E * 2;
    u16*   wc   = (u16*)p;                         p += 393216;
    u16*   qb   = (u16*)p;                         p += (size_t)BS * HH * 2;
    u16*   kb   = (u16*)p;                         p += (size_t)BS * HH * 2;
    u16*   vt   = (u16*)p;                         p += (size_t)BS * HH * 2;
    u16*   po   = (u16*)p;                         p += (size_t)BB * NSLOT * 4096 * 2;
    float* pl   = (float*)p;

    ln_wcast    <<<2048 + 192,  256, 0, stream>>>(x, gamma, beta, Wq, Wk, Wv, xn, wc);
    qkv_mfma    <<<BS / 16,     256, 0, stream>>>(xn, wc, qb, kb, vt);
    attn_partial<<<BB * NSLOT,  256, 0, stream>>>(qb, kb, vt, po, pl, out);
    attn_reduce <<<BB * 112,    256, 0, stream>>>(po, pl, out);
}

// Round 15
// 118.228 us; speedup vs baseline: 1.0601x; 1.0049x over previous
//
#include <hip/hip_runtime.h>

#define E 1024
#define HH 64
#define BB 4
#define SS 2048
#define BS (BB*SS)   // 8192 rows
#define NSLOT 144    // per-batch split-K slots: sum_{qt=0}^{31} (qt/4 + 1)

typedef unsigned short u16;
typedef short bf16x8 __attribute__((ext_vector_type(8)));
typedef float f32x4 __attribute__((ext_vector_type(4)));

#define LOG2E_O8 0.18033688011112042f   // log2(e)/8 : folds 1/sqrt(64) + exp2 domain

__device__ inline u16 f2bf(float f) {
    unsigned int u = __float_as_uint(f);
    unsigned int r = (u + 0x7FFFu + ((u >> 16) & 1u)) >> 16;   // RNE
    return (u16)r;
}
__device__ inline float bf2f(u16 h) {
    return __uint_as_float(((unsigned int)h) << 16);
}

// ---------- Kernel 1: fused LayerNorm (blocks 0..2047) + W cast (blocks 2048..2239) ----------
__global__ __launch_bounds__(256) void ln_wcast(const float* __restrict__ x,
        const float* __restrict__ gamma, const float* __restrict__ beta,
        const float* __restrict__ Wq, const float* __restrict__ Wk,
        const float* __restrict__ Wv,
        u16* __restrict__ xn, u16* __restrict__ wc) {
    const int t = threadIdx.x;
    if (blockIdx.x < 2048) {
        // ---- LayerNorm: wave-per-row, fp32 -> bf16 (gamma/beta applied here) ----
        const int w = t >> 6, lane = t & 63;
        const size_t row = (size_t)blockIdx.x * 4 + w;
        const float4* xr = (const float4*)(x + row * E);
        float4 v[4];
        #pragma unroll
        for (int i = 0; i < 4; ++i) v[i] = xr[lane + 64 * i];
        float s = 0.f, sq = 0.f;
        #pragma unroll
        for (int i = 0; i < 4; ++i) {
            s  += v[i].x + v[i].y + v[i].z + v[i].w;
            sq += v[i].x*v[i].x + v[i].y*v[i].y + v[i].z*v[i].z + v[i].w*v[i].w;
        }
        #pragma unroll
        for (int off = 32; off > 0; off >>= 1) {
            s  += __shfl_xor(s,  off);
            sq += __shfl_xor(sq, off);
        }
        const float mean = s * (1.0f / E);
        const float var  = sq * (1.0f / E) - mean * mean;
        const float rstd = rsqrtf(var + 1e-5f);
        const float4* gr = (const float4*)gamma;
        const float4* br = (const float4*)beta;
        #pragma unroll
        for (int i = 0; i < 4; ++i) {
            const float4 g  = gr[lane + 64 * i];
            const float4 bt = br[lane + 64 * i];
            ushort4 o;
            o.x = f2bf((v[i].x - mean) * rstd * g.x + bt.x);
            o.y = f2bf((v[i].y - mean) * rstd * g.y + bt.y);
            o.z = f2bf((v[i].z - mean) * rstd * g.z + bt.z);
            o.w = f2bf((v[i].w - mean) * rstd * g.w + bt.w);
            *(ushort4*)(xn + row * E + (lane + 64 * i) * 4) = o;
        }
    } else {
        // ---- W cast -> bf16 (Wq rows pre-scaled by log2(e)/8) ----
        const int row = blockIdx.x - 2048;   // 0..191
        const float* src = (row < 64)  ? (Wq + (size_t)row * E)
                         : (row < 128) ? (Wk + (size_t)(row - 64) * E)
                                       : (Wv + (size_t)(row - 128) * E);
        const float sc = (row < 64) ? LOG2E_O8 : 1.0f;
        const float4 v = *(const float4*)(src + t * 4);
        ushort4 o;
        o.x = f2bf(v.x * sc); o.y = f2bf(v.y * sc);
        o.z = f2bf(v.z * sc); o.w = f2bf(v.w * sc);
        *(ushort4*)(wc + (size_t)row * E + t * 4) = o;
    }
}

// ---------- Kernel 2: QKV projection, MFMA bf16, 32x96 blocks, 128-k chunks (R12) ----------
// V written pre-transposed: vt[b][h][key]
__global__ __launch_bounds__(256) void qkv_mfma(const u16* __restrict__ xn,
        const u16* __restrict__ wc,
        u16* __restrict__ qb, u16* __restrict__ kb, u16* __restrict__ vt) {
    const int mb   = blockIdx.x >> 1;
    const int half = blockIdx.x & 1;
    const int row0 = mb * 32;
    const int t = threadIdx.x;
    const int w = t >> 6, lane = t & 63;
    const int quad = lane >> 4, r15 = lane & 15;
    const int mt = w >> 1, cgrp = w & 1;
    __shared__ u16 Xs[32 * 128];   // 8 KB, per-64k-half chunk swizzle: phys = ch ^ (row&7)
    __shared__ u16 Ws[96 * 128];   // 24 KB
    f32x4 acc[3] = {};
    const int xrow = mt * 16 + r15;

    for (int kc8 = 0; kc8 < 8; ++kc8) {
        __syncthreads();
        {   // stage X tile: 32 rows x 128 k (two uint4 per thread)
            const int row = t >> 3, ch = t & 7;
            #pragma unroll
            for (int hf = 0; hf < 2; ++hf) {
                const uint4 d = *(const uint4*)(xn + (size_t)(row0 + row) * E
                                                + kc8 * 128 + hf * 64 + ch * 8);
                *(uint4*)&Xs[row * 128 + hf * 64 + (ch ^ (row & 7)) * 8] = d;
            }
        }
        #pragma unroll
        for (int i = 0; i < 6; ++i) {   // stage W tile: 96 rows x 128 k
            const int idx = i * 256 + t;
            const int wl = idx >> 4, ch16 = idx & 15;
            const int hf = ch16 >> 3, ch = ch16 & 7;
            const uint4 d = *(const uint4*)(wc + (size_t)(half * 96 + wl) * E
                                            + kc8 * 128 + hf * 64 + ch * 8);
            *(uint4*)&Ws[wl * 128 + hf * 64 + (ch ^ (wl & 7)) * 8] = d;
        }
        __syncthreads();
        #pragma unroll
        for (int kk = 0; kk < 4; ++kk) {
            const int hf = kk >> 1, q4 = (kk & 1) * 4 + quad;
            const bf16x8 af = *(const bf16x8*)&Xs[xrow * 128 + hf * 64 + (q4 ^ (xrow & 7)) * 8];
            #pragma unroll
            for (int j = 0; j < 3; ++j) {
                const int wl = (cgrp * 3 + j) * 16 + r15;
                const bf16x8 bfr = *(const bf16x8*)&Ws[wl * 128 + hf * 64 + (q4 ^ (wl & 7)) * 8];
                acc[j] = __builtin_amdgcn_mfma_f32_16x16x32_bf16(af, bfr, acc[j], 0, 0, 0);
            }
        }
    }
    const int b    = row0 >> 11;
    const int key0 = row0 & 2047;
    #pragma unroll
    for (int j = 0; j < 3; ++j) {
        const int cg  = half * 96 + cgrp * 48 + j * 16 + r15;
        const int sel = cg >> 6;
        const int col = cg & 63;
        if (sel < 2) {
            u16* base = (sel == 0) ? qb : kb;
            #pragma unroll
            for (int r = 0; r < 4; ++r) {
                const size_t row = (size_t)row0 + mt * 16 + quad * 4 + r;
                base[row * HH + col] = f2bf(acc[j][r]);
            }
        } else {
            ushort4 pk;
            pk.x = f2bf(acc[j][0]); pk.y = f2bf(acc[j][1]);
            pk.z = f2bf(acc[j][2]); pk.w = f2bf(acc[j][3]);
            *(ushort4*)(vt + (size_t)b * HH * SS + (size_t)col * SS
                           + key0 + mt * 16 + quad * 4) = pk;
        }
    }
}

// ---------- Kernel 3: split-K causal flash attention — PAIRED query tiles ----------
// Block = (b, a-group, rp: tile pair, c: 256-key chunk). The pair (qt=4a+2rp, qt+1)
// shares the same chunk set: K/V staged ONCE and each LDS fragment reused for both
// q-strips (2x MFMA per staged byte; 288 blocks vs 576). Slot layout unchanged.
__global__ __launch_bounds__(256) void attn_partial(const u16* __restrict__ qb,
        const u16* __restrict__ kb, const u16* __restrict__ vt,
        u16* __restrict__ po, float* __restrict__ pl,
        float* __restrict__ out) {
    const int bid = blockIdx.x;                 // BB * 72
    const int b   = bid / 72;
    const int s2  = bid - b * 72;               // flat pair-slot 0..71
    int a = (int)((sqrtf(4.0f * s2 + 1.0f) - 1.0f) * 0.5f);
    while ((a + 1) * (a + 2) <= s2) ++a;        // fixup (fp edge safety)
    while (a * (a + 1) > s2) --a;
    const int rem = s2 - a * (a + 1);
    const int rp  = rem / (a + 1);
    const int c   = rem - rp * (a + 1);
    const int qt0 = 4 * a + 2 * rp;             // pair (qt0, qt0+1)
    const int nc  = a + 1;
    const int t = threadIdx.x;
    const int w = t >> 6, lane = t & 63;
    const int quad = lane >> 4, r15 = lane & 15;

    __shared__ u16 Ks[4 * 64 * 64];   // 32 KB: [tile][key][h], XOR-swizzled chunks
    __shared__ u16 VT[4 * 64 * 64];   // 32 KB: [tile][h][key], XOR-swizzled chunks
    __shared__ u16 Ps[64 * 64];       // 8 KB:  [qrow][key], per-wave strips (reused per qi)

    // Q A-frags for both tiles of the pair
    bf16x8 qf0[2], qf1[2];
    #pragma unroll
    for (int qi = 0; qi < 2; ++qi) {
        const size_t qrow = ((size_t)b * SS + (qt0 + qi) * 64 + w * 16 + r15) * HH;
        qf0[qi] = *(const bf16x8*)(qb + qrow + quad * 8);
        qf1[qi] = *(const bf16x8*)(qb + qrow + 32 + quad * 8);
    }

    // tiles to stage: all 4 for interior chunks; 2rp+2 for the diagonal chunk (c==a)
    const int ntmax = (c < a) ? 4 : (2 * rp + 2);

    {   // ---- stage ALL needed tiles in one burst ----
        const int row = t >> 2, ch0 = (t & 3) * 2;
        for (int tl = 0; tl < ntmax; ++tl) {
            const int kt = (c * 4 + tl) << 6;
            const uint4* srcK = (const uint4*)(kb + ((size_t)b * SS + kt + row) * HH + ch0 * 8);
            const uint4 k0 = srcK[0], k1 = srcK[1];
            *(uint4*)&Ks[tl * 4096 + row * 64 + ((ch0    ) ^ (row & 7)) * 8] = k0;
            *(uint4*)&Ks[tl * 4096 + row * 64 + ((ch0 + 1) ^ (row & 7)) * 8] = k1;
            const uint4* srcV = (const uint4*)(vt + (size_t)b * HH * SS + (size_t)row * SS
                                               + kt + ch0 * 8);
            const uint4 v0 = srcV[0], v1 = srcV[1];
            *(uint4*)&VT[tl * 4096 + row * 64 + ((ch0    ) ^ (row & 7)) * 8] = v0;
            *(uint4*)&VT[tl * 4096 + row * 64 + ((ch0 + 1) ^ (row & 7)) * 8] = v1;
        }
    }
    __syncthreads();   // the ONLY block-wide barrier

    f32x4 o[2][4] = {};
    float l_[2][4] = {};

    for (int tl = 0; tl < ntmax; ++tl) {
        const int tile = c * 4 + tl;
        const u16* KsT = &Ks[tl * 4096];
        const u16* VTT = &VT[tl * 4096];

        // K/V fragments: loaded ONCE per tile, reused by both q-strips
        bf16x8 kf0[4], kf1[4], vf0[4], vf1[4];
        #pragma unroll
        for (int nt = 0; nt < 4; ++nt) {
            const int krow = nt * 16 + r15;
            kf0[nt] = *(const bf16x8*)&KsT[krow * 64 + ((    quad) ^ (krow & 7)) * 8];
            kf1[nt] = *(const bf16x8*)&KsT[krow * 64 + ((4 + quad) ^ (krow & 7)) * 8];
            vf0[nt] = *(const bf16x8*)&VTT[krow * 64 + ((    quad) ^ (krow & 7)) * 8];
            vf1[nt] = *(const bf16x8*)&VTT[krow * 64 + ((4 + quad) ^ (krow & 7)) * 8];
        }

        #pragma unroll
        for (int qi = 0; qi < 2; ++qi) {
            const int qt_i = qt0 + qi;
            if (tile > qt_i) continue;       // only fires: c==a, qi==0, tl==2rp+1

            // S strip = Q K^T (16 x 64)
            f32x4 s4[4] = {};
            #pragma unroll
            for (int nt = 0; nt < 4; ++nt) {
                s4[nt] = __builtin_amdgcn_mfma_f32_16x16x32_bf16(qf0[qi], kf0[nt], s4[nt], 0, 0, 0);
                s4[nt] = __builtin_amdgcn_mfma_f32_16x16x32_bf16(qf1[qi], kf1[nt], s4[nt], 0, 0, 0);
            }
            if (tile == qt_i) {   // diagonal tile: mask key > query
                #pragma unroll
                for (int nt = 0; nt < 4; ++nt)
                    #pragma unroll
                    for (int r = 0; r < 4; ++r)
                        if (nt * 16 + r15 > w * 16 + quad * 4 + r) s4[nt][r] = -INFINITY;
            }

            // un-shifted softmax: p = exp2(s). Row sums deferred (per-lane).
            float p[4][4];
            #pragma unroll
            for (int r = 0; r < 4; ++r) {
                #pragma unroll
                for (int nt = 0; nt < 4; ++nt)
                    p[nt][r] = __builtin_amdgcn_exp2f(s4[nt][r]);
                l_[qi][r] += (p[0][r] + p[1][r]) + (p[2][r] + p[3][r]);
            }

            // P strip -> LDS (per-wave strip, reused across qi; in-wave ordering)
            #pragma unroll
            for (int nt = 0; nt < 4; ++nt)
                #pragma unroll
                for (int r = 0; r < 4; ++r) {
                    const int prow = w * 16 + quad * 4 + r;
                    const int col  = nt * 16 + r15;
                    Ps[prow * 64 + (((col >> 3) ^ (prow & 7)) * 8) + (col & 7)] = f2bf(p[nt][r]);
                }
            const int arow = w * 16 + r15;
            const bf16x8 pf0 = *(const bf16x8*)&Ps[arow * 64 + ((    quad) ^ (arow & 7)) * 8];
            const bf16x8 pf1 = *(const bf16x8*)&Ps[arow * 64 + ((4 + quad) ^ (arow & 7)) * 8];

            // O strip += P V
            #pragma unroll
            for (int ht = 0; ht < 4; ++ht) {
                o[qi][ht] = __builtin_amdgcn_mfma_f32_16x16x32_bf16(pf0, vf0[ht], o[qi][ht], 0, 0, 0);
                o[qi][ht] = __builtin_amdgcn_mfma_f32_16x16x32_bf16(pf1, vf1[ht], o[qi][ht], 0, 0, 0);
            }
        }
    }

    // one row-sum reduction per block per tile-pair
    #pragma unroll
    for (int qi = 0; qi < 2; ++qi)
        #pragma unroll
        for (int r = 0; r < 4; ++r) {
            l_[qi][r] += __shfl_xor(l_[qi][r], 1); l_[qi][r] += __shfl_xor(l_[qi][r], 2);
            l_[qi][r] += __shfl_xor(l_[qi][r], 4); l_[qi][r] += __shfl_xor(l_[qi][r], 8);
        }

    #pragma unroll
    for (int qi = 0; qi < 2; ++qi) {
        const int qt_i = qt0 + qi;
        if (nc == 1) {   // a==0: pair saw all keys -> write out directly
            #pragma unroll
            for (int r = 0; r < 4; ++r) {
                const float inv = 1.0f / l_[qi][r];
                const size_t orow = ((size_t)b * SS + qt_i * 64 + w * 16 + quad * 4 + r) * HH;
                #pragma unroll
                for (int ht = 0; ht < 4; ++ht)
                    out[orow + ht * 16 + r15] = o[qi][ht][r] * inv;
            }
        } else {
            const int slot = b * NSLOT + 2 * a * (a + 1) + (2 * rp + qi) * (a + 1) + c;
            #pragma unroll
            for (int r = 0; r < 4; ++r) {
                const int q = w * 16 + quad * 4 + r;
                #pragma unroll
                for (int ht = 0; ht < 4; ++ht)
                    po[(size_t)slot * 4096 + q * 64 + ht * 16 + r15] = f2bf(o[qi][ht][r]);
                if (r15 == 0) pl[slot * 64 + q] = l_[qi][r];
            }
        }
    }
}

// ---------- Kernel 4: split-K reduce — plain sums (po is bf16), qt>=4 only ----------
__global__ __launch_bounds__(256) void attn_reduce(const u16* __restrict__ po,
        const float* __restrict__ pl, float* __restrict__ out) {
    const int bid = blockIdx.x;            // BB*28*4 = 448 (qt 4..31 only)
    const int b = bid / 112, rem = bid - b * 112;
    const int qt = 4 + (rem >> 2), qq = rem & 3;
    const int a = qt >> 2, r_ = qt & 3;
    const int nc = a + 1;
    const int sbase = b * NSLOT + 2 * a * (a + 1) + r_ * (a + 1);
    const int t = threadIdx.x;
    const int h = t & 63, qr = t >> 6;
    #pragma unroll
    for (int i = 0; i < 4; ++i) {
        const int q = qq * 16 + qr * 4 + i;   // query within 64-tile
        float osum = 0.f, lsum = 0.f;
        for (int cidx = 0; cidx < nc; ++cidx) {
            osum += bf2f(po[(size_t)(sbase + cidx) * 4096 + q * 64 + h]);
            lsum += pl[(sbase + cidx) * 64 + q];
        }
        out[((size_t)b * SS + (qt << 6) + q) * HH + h] = osum / lsum;
    }
}

// ---------- launch ----------
extern "C" void kernel_launch(void* const* d_in, const int* in_sizes, int n_in,
                              void* d_out, int out_size, void* d_ws, size_t ws_size,
                              hipStream_t stream) {
    const float* x     = (const float*)d_in[0];
    const float* gamma = (const float*)d_in[1];
    const float* beta  = (const float*)d_in[2];
    const float* Wq    = (const float*)d_in[3];
    const float* Wk    = (const float*)d_in[4];
    const float* Wv    = (const float*)d_in[5];
    float* out = (float*)d_out;

    // ws layout: xn 16.78MB | wc 384KB | qb/kb/vt 1MB each | po 4.72MB (bf16) | pl 144KB
    char* p = (char*)d_ws;
    u16*   xn   = (u16*)p;                         p += (size_t)BS * E * 2;
    u16*   wc   = (u16*)p;                         p += 393216;
    u16*   qb   = (u16*)p;                         p += (size_t)BS * HH * 2;
    u16*   kb   = (u16*)p;                         p += (size_t)BS * HH * 2;
    u16*   vt   = (u16*)p;                         p += (size_t)BS * HH * 2;
    u16*   po   = (u16*)p;                         p += (size_t)BB * NSLOT * 4096 * 2;
    float* pl   = (float*)p;

    ln_wcast    <<<2048 + 192,  256, 0, stream>>>(x, gamma, beta, Wq, Wk, Wv, xn, wc);
    qkv_mfma    <<<BS / 16,     256, 0, stream>>>(xn, wc, qb, kb, vt);
    attn_partial<<<BB * 72,     256, 0, stream>>>(qb, kb, vt, po, pl, out);
    attn_reduce <<<BB * 112,    256, 0, stream>>>(po, pl, out);
}